// Round 1
// baseline (145.800 us; speedup 1.0000x reference)
//
#include <hip/hip_runtime.h>
#include <hip/hip_bf16.h>
#include <math.h>

#define BATCH 4096
#define DIM 128
#define TWO_B 8192

typedef __bf16 bf16;
typedef __bf16 bf16x8 __attribute__((ext_vector_type(8)));
typedef float floatx4 __attribute__((ext_vector_type(4)));

// Kernel 1: per-row L2 normalize both inputs -> bf16 reps[2B][D]; positives in fp32.
// One wave (64 lanes) per batch row; lane l handles elements l and l+64.
__global__ __launch_bounds__(64) void norm_kernel(const float* __restrict__ p1,
                                                  const float* __restrict__ p2,
                                                  bf16* __restrict__ reps,
                                                  float* __restrict__ pos) {
    int b = blockIdx.x;
    int l = threadIdx.x;
    const float* r1 = p1 + (size_t)b * DIM;
    const float* r2 = p2 + (size_t)b * DIM;
    float x0 = r1[l], x1 = r1[l + 64];
    float y0 = r2[l], y1 = r2[l + 64];
    float s1 = x0 * x0 + x1 * x1;
    float s2 = y0 * y0 + y1 * y1;
    float s12 = x0 * y0 + x1 * y1;
    #pragma unroll
    for (int off = 32; off; off >>= 1) {
        s1  += __shfl_xor(s1, off);
        s2  += __shfl_xor(s2, off);
        s12 += __shfl_xor(s12, off);
    }
    float i1 = 1.0f / fmaxf(sqrtf(s1), 1e-12f);
    float i2 = 1.0f / fmaxf(sqrtf(s2), 1e-12f);
    bf16* o1 = reps + (size_t)b * DIM;
    bf16* o2 = reps + (size_t)(b + BATCH) * DIM;
    o1[l]      = (bf16)(x0 * i1);
    o1[l + 64] = (bf16)(x1 * i1);
    o2[l]      = (bf16)(y0 * i2);
    o2[l + 64] = (bf16)(y1 * i2);
    if (l == 0) pos[b] = s12 * i1 * i2;
}

// Kernel 2: 128x128 sim tile per block; fused exp(sim/T) + diagonal mask + row-sum.
// 4 waves in 2x2, each computes a 64x64 region as 4x4 MFMA 16x16x32 bf16 tiles.
// LDS tiles are 128x128 bf16 (32 KB each, 64 KB total). 16B chunks XOR-swizzled
// by (row & 15) so the frag reads (16 lanes x 16 different rows) hit all 16
// chunk positions -> 2-way bank aliasing only (free on CDNA4).
__global__ __launch_bounds__(256) void sim_kernel(const bf16* __restrict__ reps,
                                                  float* __restrict__ denom) {
    __shared__ alignas(16) bf16 As[128 * 128];
    __shared__ alignas(16) bf16 Bs[128 * 128];
    int tid = threadIdx.x;
    int brow = blockIdx.y, bcol = blockIdx.x;

    const bf16* ga = reps + (size_t)brow * 128 * DIM;
    const bf16* gb = reps + (size_t)bcol * 128 * DIM;
    #pragma unroll
    for (int i = 0; i < 8; ++i) {
        int c = tid + i * 256;          // 2048 chunks of 16B
        int r = c >> 4;                 // row 0..127
        int cc = c & 15;                // 16B chunk within row
        int sw = (cc ^ (r & 15)) * 8;   // swizzled element offset
        *(bf16x8*)&As[r * 128 + sw] = *(const bf16x8*)&ga[(size_t)r * DIM + cc * 8];
        *(bf16x8*)&Bs[r * 128 + sw] = *(const bf16x8*)&gb[(size_t)r * DIM + cc * 8];
    }
    __syncthreads();

    int wid = tid >> 6;
    int lane = tid & 63;
    int wm = wid >> 1, wn = wid & 1;    // 2x2 wave grid, 64x64 each
    int lr = lane & 15;                 // A: m within tile; B: n within tile
    int q = lane >> 4;                  // quad -> k = q*8 + j

    floatx4 acc[4][4] = {};
    #pragma unroll
    for (int k0 = 0; k0 < 128; k0 += 32) {
        int c0 = (k0 >> 3) + q;         // 16B chunk index along K
        bf16x8 afrag[4], bfrag[4];
        #pragma unroll
        for (int mi = 0; mi < 4; ++mi) {
            int m = wm * 64 + mi * 16 + lr;
            afrag[mi] = *(const bf16x8*)&As[m * 128 + ((c0 ^ lr) * 8)];
        }
        #pragma unroll
        for (int ni = 0; ni < 4; ++ni) {
            int n = wn * 64 + ni * 16 + lr;
            bfrag[ni] = *(const bf16x8*)&Bs[n * 128 + ((c0 ^ lr) * 8)];
        }
        #pragma unroll
        for (int mi = 0; mi < 4; ++mi)
            #pragma unroll
            for (int ni = 0; ni < 4; ++ni)
                acc[mi][ni] = __builtin_amdgcn_mfma_f32_16x16x32_bf16(
                    afrag[mi], bfrag[ni], acc[mi][ni], 0, 0, 0);
    }

    // Epilogue: C/D layout col = lane&15, row = q*4 + reg.
    int grow_base = brow * 128 + wm * 64;
    int gcol_lane = bcol * 128 + wn * 64 + lr;
    #pragma unroll
    for (int mi = 0; mi < 4; ++mi) {
        #pragma unroll
        for (int reg = 0; reg < 4; ++reg) {
            int grow = grow_base + mi * 16 + q * 4 + reg;
            float s = 0.0f;
            #pragma unroll
            for (int ni = 0; ni < 4; ++ni) {
                int gcol = gcol_lane + ni * 16;
                float e = __expf(acc[mi][ni][reg] * 2.0f);  // 1/TEMP = 2
                s += (grow == gcol) ? 0.0f : e;             // exact diag mask
            }
            s += __shfl_xor(s, 1);
            s += __shfl_xor(s, 2);
            s += __shfl_xor(s, 4);
            s += __shfl_xor(s, 8);
            if (lr == 0) atomicAdd(&denom[grow], s);
        }
    }
}

// Kernel 3: loss = mean_r( log(denom[r]) - 2*pos[r mod B] )
__global__ __launch_bounds__(256) void loss_kernel(const float* __restrict__ denom,
                                                   const float* __restrict__ pos,
                                                   float* __restrict__ out) {
    int tid = threadIdx.x;
    float acc = 0.0f;
    for (int r = tid; r < TWO_B; r += 256)
        acc += logf(denom[r]) - pos[r & (BATCH - 1)] * 2.0f;
    #pragma unroll
    for (int off = 32; off; off >>= 1) acc += __shfl_xor(acc, off);
    __shared__ float sred[4];
    int lane = tid & 63, wid = tid >> 6;
    if (lane == 0) sred[wid] = acc;
    __syncthreads();
    if (tid == 0)
        out[0] = (sred[0] + sred[1] + sred[2] + sred[3]) / (float)TWO_B;
}

extern "C" void kernel_launch(void* const* d_in, const int* in_sizes, int n_in,
                              void* d_out, int out_size, void* d_ws, size_t ws_size,
                              hipStream_t stream) {
    const float* p1 = (const float*)d_in[0];
    const float* p2 = (const float*)d_in[1];
    float* out = (float*)d_out;

    char* ws = (char*)d_ws;
    bf16* reps = (bf16*)ws;                                   // 8192*128*2 = 2 MB
    float* pos = (float*)(ws + (size_t)TWO_B * DIM * sizeof(bf16));  // 16 KB
    float* denom = pos + BATCH;                               // 32 KB

    hipMemsetAsync(denom, 0, TWO_B * sizeof(float), stream);
    norm_kernel<<<BATCH, 64, 0, stream>>>(p1, p2, reps, pos);
    sim_kernel<<<dim3(64, 64), 256, 0, stream>>>(reps, denom);
    loss_kernel<<<1, 256, 0, stream>>>(denom, pos, out);
}

// Round 2
// 103.582 us; speedup vs baseline: 1.4076x; 1.4076x over previous
//
#include <hip/hip_runtime.h>
#include <hip/hip_bf16.h>
#include <math.h>

#define BATCH 4096
#define DIM 128
#define TWO_B 8192

typedef __bf16 bf16;
typedef __bf16 bf16x8 __attribute__((ext_vector_type(8)));
typedef float floatx4 __attribute__((ext_vector_type(4)));

// Blocked, MFMA-fragment-native layout for normalized reps:
//   element (row, k) -> repsL[(row>>4)*2048 + (k>>3)*128 + (row&15)*8 + (k&7)]
// A wave's 16x16x32 A/B fragment load (16 rows x 16B k-chunk x 4 quads) is then
// ONE fully-coalesced 1KB global_load_dwordx4 per fragment. 2MB total -> L2-resident.

// Kernel 1: per-row L2 normalize -> blocked bf16 reps; positives fp32; zero denom.
__global__ __launch_bounds__(64) void norm_kernel(const float* __restrict__ p1,
                                                  const float* __restrict__ p2,
                                                  bf16* __restrict__ repsL,
                                                  float* __restrict__ pos,
                                                  float* __restrict__ denom) {
    int b = blockIdx.x;
    int l = threadIdx.x;
    const float* r1 = p1 + (size_t)b * DIM;
    const float* r2 = p2 + (size_t)b * DIM;
    float x0 = r1[l], x1 = r1[l + 64];
    float y0 = r2[l], y1 = r2[l + 64];
    float s1 = x0 * x0 + x1 * x1;
    float s2 = y0 * y0 + y1 * y1;
    float s12 = x0 * y0 + x1 * y1;
    #pragma unroll
    for (int off = 32; off; off >>= 1) {
        s1  += __shfl_xor(s1, off);
        s2  += __shfl_xor(s2, off);
        s12 += __shfl_xor(s12, off);
    }
    float i1 = 1.0f / fmaxf(sqrtf(s1), 1e-12f);
    float i2 = 1.0f / fmaxf(sqrtf(s2), 1e-12f);

    int row1 = b, row2 = b + BATCH;
    size_t a1 = (size_t)(row1 >> 4) * 2048 + (row1 & 15) * 8;
    size_t a2 = (size_t)(row2 >> 4) * 2048 + (row2 & 15) * 8;
    int c0 = (l >> 3) * 128 + (l & 7);      // k = l
    int c1 = c0 + 8 * 128;                  // k = l + 64
    repsL[a1 + c0] = (bf16)(x0 * i1);
    repsL[a1 + c1] = (bf16)(x1 * i1);
    repsL[a2 + c0] = (bf16)(y0 * i2);
    repsL[a2 + c1] = (bf16)(y1 * i2);

    if (l == 0) { pos[b] = s12 * i1 * i2; denom[b] = 0.0f; denom[b + BATCH] = 0.0f; }
}

// Kernel 2: one WAVE per 64x64 sim tile (tn >= tm, symmetry-halved).
// No LDS, no barriers: fragments loaded straight from the blocked layout.
// Triangular tile set {(tm,tn): 0<=tm<=tn<128} (8256 tiles) folded into a
// 129 x 64 rectangle: wave (r, c) -> (r, r+c) if c < 128-r else
// (127-r, 127-r + c-(128-r)).
// Off-diagonal tiles add exp-sums to BOTH denom[rows] (row sums) and
// denom[cols] (column sums == symmetric counterpart tile's row sums).
__global__ __launch_bounds__(256, 4) void sim_kernel(const bf16* __restrict__ repsL,
                                                     float* __restrict__ denom) {
    int wid = threadIdx.x >> 6;
    int lane = threadIdx.x & 63;
    int r = blockIdx.y * 4 + wid;   // [0, 64)
    int c = blockIdx.x;             // [0, 129)
    int tm, tn;
    if (c < 128 - r) { tm = r; tn = r + c; }
    else             { tm = 127 - r; tn = tm + (c - (128 - r)); }

    int lr = lane & 15;             // row/col within 16-tile
    int q  = lane >> 4;             // quad

    const char* base = (const char*)repsL;
    // fragment byte addr: Rblk*4096 + chunk*256 + lr*16 ; chunk = kstep*4 + q
    int aoff = tm * 4 * 4096 + q * 256 + lr * 16;
    int boff = tn * 4 * 4096 + q * 256 + lr * 16;

    floatx4 acc[4][4] = {};
    #pragma unroll
    for (int ks = 0; ks < 4; ++ks) {        // K = 128 in steps of 32
        bf16x8 af[4], bfr[4];
        #pragma unroll
        for (int mi = 0; mi < 4; ++mi)
            af[mi] = *(const bf16x8*)(base + aoff + mi * 4096 + ks * 1024);
        #pragma unroll
        for (int ni = 0; ni < 4; ++ni)
            bfr[ni] = *(const bf16x8*)(base + boff + ni * 4096 + ks * 1024);
        #pragma unroll
        for (int mi = 0; mi < 4; ++mi)
            #pragma unroll
            for (int ni = 0; ni < 4; ++ni)
                acc[mi][ni] = __builtin_amdgcn_mfma_f32_16x16x32_bf16(
                    af[mi], bfr[ni], acc[mi][ni], 0, 0, 0);
    }

    // Epilogue. C/D layout: col = lr, row = q*4 + reg.
    bool diag = (tm == tn);
    int growb = tm * 64 + q * 4;
    int gcolb = tn * 64 + lr;
    float cs[4] = {0.0f, 0.0f, 0.0f, 0.0f};
    #pragma unroll
    for (int mi = 0; mi < 4; ++mi) {
        #pragma unroll
        for (int reg = 0; reg < 4; ++reg) {
            int grow = growb + mi * 16 + reg;
            float s = 0.0f;
            #pragma unroll
            for (int ni = 0; ni < 4; ++ni) {
                float e = __expf(acc[mi][ni][reg] * 2.0f);   // 1/TEMP = 2
                if (diag && (grow == gcolb + ni * 16)) e = 0.0f;  // exact diag mask
                s += e;
                cs[ni] += e;
            }
            s += __shfl_xor(s, 1);
            s += __shfl_xor(s, 2);
            s += __shfl_xor(s, 4);
            s += __shfl_xor(s, 8);
            if (lr == 0) atomicAdd(&denom[grow], s);
        }
    }
    if (!diag) {
        #pragma unroll
        for (int ni = 0; ni < 4; ++ni) {
            cs[ni] += __shfl_xor(cs[ni], 16);
            cs[ni] += __shfl_xor(cs[ni], 32);
        }
        if (q == 0) {
            #pragma unroll
            for (int ni = 0; ni < 4; ++ni)
                atomicAdd(&denom[gcolb + ni * 16], cs[ni]);
        }
    }
}

// Kernel 3: loss = mean_r( log(denom[r]) - 2*pos[r mod B] )
__global__ __launch_bounds__(1024) void loss_kernel(const float* __restrict__ denom,
                                                    const float* __restrict__ pos,
                                                    float* __restrict__ out) {
    int tid = threadIdx.x;
    float acc = 0.0f;
    for (int i = tid; i < TWO_B; i += 1024)
        acc += __logf(denom[i]) - 2.0f * pos[i & (BATCH - 1)];
    #pragma unroll
    for (int off = 32; off; off >>= 1) acc += __shfl_xor(acc, off);
    __shared__ float sred[16];
    int lane = tid & 63, wid = tid >> 6;
    if (lane == 0) sred[wid] = acc;
    __syncthreads();
    if (tid == 0) {
        float t = 0.0f;
        #pragma unroll
        for (int i = 0; i < 16; ++i) t += sred[i];
        out[0] = t / (float)TWO_B;
    }
}

extern "C" void kernel_launch(void* const* d_in, const int* in_sizes, int n_in,
                              void* d_out, int out_size, void* d_ws, size_t ws_size,
                              hipStream_t stream) {
    const float* p1 = (const float*)d_in[0];
    const float* p2 = (const float*)d_in[1];
    float* out = (float*)d_out;

    char* ws = (char*)d_ws;
    bf16* repsL = (bf16*)ws;                                          // 2 MB
    float* pos = (float*)(ws + (size_t)TWO_B * DIM * sizeof(bf16));   // 16 KB
    float* denom = pos + BATCH;                                       // 32 KB

    norm_kernel<<<BATCH, 64, 0, stream>>>(p1, p2, repsL, pos, denom);
    sim_kernel<<<dim3(129, 16), 256, 0, stream>>>(repsL, denom);
    loss_kernel<<<1, 1024, 0, stream>>>(denom, pos, out);
}

// Round 3
// 91.676 us; speedup vs baseline: 1.5904x; 1.1299x over previous
//
#include <hip/hip_runtime.h>
#include <hip/hip_bf16.h>
#include <math.h>

#define BATCH 4096
#define DIM 128
#define TWO_B 8192

typedef __bf16 bf16;
typedef __bf16 bf16x8 __attribute__((ext_vector_type(8)));
typedef float floatx4 __attribute__((ext_vector_type(4)));

// Blocked, MFMA-fragment-native layout for normalized reps:
//   element (row, k) -> repsL[(row>>4)*2048 + (k>>3)*128 + (row&15)*8 + (k&7)]
// One 16x16x32 fragment load = one fully-coalesced 1KB global_load_dwordx4.

// Kernel 1: per-row L2 normalize -> blocked bf16 reps; positives; zero out[0].
__global__ __launch_bounds__(64) void norm_kernel(const float* __restrict__ p1,
                                                  const float* __restrict__ p2,
                                                  bf16* __restrict__ repsL,
                                                  float* __restrict__ pos,
                                                  float* __restrict__ out) {
    int b = blockIdx.x;
    int l = threadIdx.x;
    const float* r1 = p1 + (size_t)b * DIM;
    const float* r2 = p2 + (size_t)b * DIM;
    float x0 = r1[l], x1 = r1[l + 64];
    float y0 = r2[l], y1 = r2[l + 64];
    float s1 = x0 * x0 + x1 * x1;
    float s2 = y0 * y0 + y1 * y1;
    float s12 = x0 * y0 + x1 * y1;
    #pragma unroll
    for (int off = 32; off; off >>= 1) {
        s1  += __shfl_xor(s1, off);
        s2  += __shfl_xor(s2, off);
        s12 += __shfl_xor(s12, off);
    }
    float i1 = 1.0f / fmaxf(sqrtf(s1), 1e-12f);
    float i2 = 1.0f / fmaxf(sqrtf(s2), 1e-12f);

    int row1 = b, row2 = b + BATCH;
    size_t a1 = (size_t)(row1 >> 4) * 2048 + (row1 & 15) * 8;
    size_t a2 = (size_t)(row2 >> 4) * 2048 + (row2 & 15) * 8;
    int c0 = (l >> 3) * 128 + (l & 7);      // k = l
    int c1 = c0 + 8 * 128;                  // k = l + 64
    repsL[a1 + c0] = (bf16)(x0 * i1);
    repsL[a1 + c1] = (bf16)(x1 * i1);
    repsL[a2 + c0] = (bf16)(y0 * i2);
    repsL[a2 + c1] = (bf16)(y1 * i2);

    if (l == 0) {
        pos[b] = s12 * i1 * i2;
        if (b == 0) out[0] = 0.0f;          // reduce kernel atomicAdds into out
    }
}

// Kernel 2: 128x128 sim region per block (4 waves, 2x2 of 64x64 wave-tiles),
// triangular block set TM<=TN (2080 blocks). No LDS, no barriers, NO ATOMICS:
// each 64x64 wave-tile (tm,tn), tm<=tn, writes its 64 row-exp-sums to slot
// part[tn][rows of tm] and (off-diag) its 64 col-exp-sums to part[tm][rows of tn].
// For any row r in 64-block j the 128 slots k are written exactly once:
//   k=j..127 by row-parts of tiles (j,k); k=0..j-1 by col-parts of tiles (k,j).
__global__ __launch_bounds__(256) void sim_kernel(const bf16* __restrict__ repsL,
                                                  float* __restrict__ part) {
    int wid = threadIdx.x >> 6;
    int lane = threadIdx.x & 63;
    int r = blockIdx.y;             // [0, 32)
    int c = blockIdx.x;             // [0, 65)
    int TM, TN;
    if (c < 64 - r) { TM = r; TN = r + c; }
    else            { TM = 63 - r; TN = TM + (c - (64 - r)); }
    int wm = wid >> 1, wn = wid & 1;
    if (TM == TN && wm == 1 && wn == 0) return;   // mirror quadrant of diag block
    int tm = TM * 2 + wm;           // 64-tile coords, tm <= tn
    int tn = TN * 2 + wn;

    int lr = lane & 15;
    int q  = lane >> 4;

    const char* base = (const char*)repsL;
    const char* ab = base + tm * 16384 + q * 256 + lr * 16;
    const char* bb = base + tn * 16384 + q * 256 + lr * 16;

    floatx4 acc[4][4] = {};
    #pragma unroll
    for (int ks = 0; ks < 4; ++ks) {
        bf16x8 af[4], bf[4];
        #pragma unroll
        for (int mi = 0; mi < 4; ++mi)
            af[mi] = *(const bf16x8*)(ab + mi * 4096 + ks * 1024);
        #pragma unroll
        for (int ni = 0; ni < 4; ++ni)
            bf[ni] = *(const bf16x8*)(bb + ni * 4096 + ks * 1024);
        #pragma unroll
        for (int mi = 0; mi < 4; ++mi)
            #pragma unroll
            for (int ni = 0; ni < 4; ++ni)
                acc[mi][ni] = __builtin_amdgcn_mfma_f32_16x16x32_bf16(
                    af[mi], bf[ni], acc[mi][ni], 0, 0, 0);
    }

    // Epilogue. C/D layout: col = lr (+ni*16), row = q*4 + reg (+mi*16).
    // exp(sim/T) = exp(2*sim) = exp2(sim * 2*log2(e))
    const float K2 = 2.8853900817779268f;
    bool diag = (tm == tn);
    int growb = tm * 64 + q * 4;
    int gcolb = tn * 64 + lr;
    float cs[4] = {0.0f, 0.0f, 0.0f, 0.0f};
    #pragma unroll
    for (int mi = 0; mi < 4; ++mi) {
        #pragma unroll
        for (int reg = 0; reg < 4; ++reg) {
            int grow = growb + mi * 16 + reg;
            float s = 0.0f;
            #pragma unroll
            for (int ni = 0; ni < 4; ++ni) {
                float e = exp2f(acc[mi][ni][reg] * K2);
                if (diag && (grow == gcolb + ni * 16)) e = 0.0f;  // exact diag mask
                s += e;
                cs[ni] += e;
            }
            s += __shfl_xor(s, 1);
            s += __shfl_xor(s, 2);
            s += __shfl_xor(s, 4);
            s += __shfl_xor(s, 8);
            if (lr == 0) part[(size_t)tn * TWO_B + grow] = s;   // row-part, slot tn
        }
    }
    if (!diag) {
        #pragma unroll
        for (int ni = 0; ni < 4; ++ni) {
            cs[ni] += __shfl_xor(cs[ni], 16);
            cs[ni] += __shfl_xor(cs[ni], 32);
        }
        if (q == 0) {
            #pragma unroll
            for (int ni = 0; ni < 4; ++ni)
                part[(size_t)tm * TWO_B + gcolb + ni * 16] = cs[ni];  // col-part, slot tm
        }
    }
}

// Kernel 3: denom[r] = sum_k part[k][r]; loss = mean(log(denom) - 2*pos).
__global__ __launch_bounds__(256) void reduce_kernel(const float* __restrict__ part,
                                                     const float* __restrict__ pos,
                                                     float* __restrict__ out) {
    int tid = threadIdx.x;
    int rr = blockIdx.x * 256 + tid;     // one row per thread, coalesced over k
    float s = 0.0f;
    #pragma unroll 8
    for (int k = 0; k < 128; ++k)
        s += part[(size_t)k * TWO_B + rr];
    float v = __logf(s) - 2.0f * pos[rr & (BATCH - 1)];
    #pragma unroll
    for (int off = 32; off; off >>= 1) v += __shfl_xor(v, off);
    __shared__ float sred[4];
    int lane = tid & 63, wid = tid >> 6;
    if (lane == 0) sred[wid] = v;
    __syncthreads();
    if (tid == 0)
        atomicAdd(out, (sred[0] + sred[1] + sred[2] + sred[3]) * (1.0f / TWO_B));
}

extern "C" void kernel_launch(void* const* d_in, const int* in_sizes, int n_in,
                              void* d_out, int out_size, void* d_ws, size_t ws_size,
                              hipStream_t stream) {
    const float* p1 = (const float*)d_in[0];
    const float* p2 = (const float*)d_in[1];
    float* out = (float*)d_out;

    char* ws = (char*)d_ws;
    bf16* repsL = (bf16*)ws;                                          // 2 MB
    float* pos = (float*)(ws + (size_t)TWO_B * DIM * sizeof(bf16));   // 16 KB
    float* part = pos + BATCH;                                        // 128*8192*4 = 4 MB

    norm_kernel<<<BATCH, 64, 0, stream>>>(p1, p2, repsL, pos, out);
    sim_kernel<<<dim3(65, 32), 256, 0, stream>>>(repsL, part);
    reduce_kernel<<<TWO_B / 256, 256, 0, stream>>>(part, pos, out);
}